// Round 8
// baseline (78.524 us; speedup 1.0000x reference)
//
#include <hip/hip_runtime.h>
#include <hip/hip_fp16.h>
#include <math.h>

#define TT 8192
#define FF 64

typedef float f32x4 __attribute__((ext_vector_type(4)));

__device__ __forceinline__ float rcpf(float x) { return __builtin_amdgcn_rcpf(x); }

// ---- prep: wp[j*64+i] = {softmax(W)[i][j], PW[i][j]} packed half2 ----
__global__ void prep_kernel(const float* __restrict__ W,
                            const float* __restrict__ PW,
                            __half2* __restrict__ wp) {
    const int lane = threadIdx.x;   // j
    const int wv   = threadIdx.y;   // 0..3
    for (int it = 0; it < 16; ++it) {
        const int r = wv * 16 + it; // i
        float v = W[r * 64 + lane];
        float m = v;
        #pragma unroll
        for (int off = 32; off >= 1; off >>= 1)
            m = fmaxf(m, __shfl_xor(m, off, 64));
        float e = __expf(v - m);
        float s = e;
        #pragma unroll
        for (int off = 32; off >= 1; off >>= 1)
            s += __shfl_xor(s, off, 64);
        const float w = e * rcpf(s);
        wp[lane * 64 + r] = __floats2half2_rn(w, PW[r * 64 + lane]);
    }
}

// ---- fused main: 1024 thr, 64-row tile; FIR + coupling(i-blk 8, j-split) + proj ----
__global__ __launch_bounds__(1024, 8)
void mcao_main(const float* __restrict__ x,
               const __half2* __restrict__ wp,
               const float* __restrict__ pb,
               const float* __restrict__ kap,
               const float* __restrict__ coeffs,
               float* __restrict__ out,
               float* __restrict__ memout) {
    // phase-unioned LDS: [0,29184) xs 114x64 f32  ->  tS 64x65 f32 [0,16640)
    //                                                 uh 64x66 f16 [16640,25088)
    //                                                 xh 64x66 f16 [25088,33536)
    // P2 (final bracket, f32 64x65) reuses [16640,33280) after j-loop.
    // wpS half2 64x64 at [33536,49920).
    __shared__ __align__(16) char smem[49920];
    float*   xs  = (float*)smem;
    float*   tS  = (float*)smem;
    __half*  uh  = (__half*)(smem + 16640);
    __half*  xh  = (__half*)(smem + 25088);
    float*   P2  = (float*)(smem + 16640);
    __half2* wpS = (__half2*)(smem + 33536);

    const int tid  = threadIdx.x;
    const int lane = tid & 63;
    const int wv   = tid >> 6;              // 0..15

    // XCD-aware bijective swizzle (512 blocks -> 64 consecutive tiles/XCD)
    const int sw = ((int)blockIdx.x & 7) * 64 + ((int)blockIdx.x >> 3);
    const int b  = sw >> 7;
    const int t0 = (sw & 127) * 64;
    const float* xb = x + (size_t)b * TT * FF;

    // ---- stage xs rows [t0-50, t0+64) + wpS ----
    for (int i4 = tid; i4 < 114 * 16; i4 += 1024) {
        const int s = i4 >> 4, f4 = i4 & 15, t = t0 - 50 + s;
        f32x4 v = {0.f, 0.f, 0.f, 0.f};
        if (t >= 0) v = *(const f32x4*)(xb + (size_t)t * 64 + f4 * 4);
        *(f32x4*)(&xs[i4 * 4]) = v;
    }
    ((f32x4*)wpS)[tid] = ((const f32x4*)wp)[tid];
    __syncthreads();                                    // bar1

    // ---- FIR from xs: wave owns rows 4wv..4wv+3 ----
    float macc[4] = {0.f, 0.f, 0.f, 0.f};
    #pragma unroll
    for (int s = 0; s < 54; ++s) {
        const float xv = xs[(4 * wv + s) * 64 + lane];
        #pragma unroll
        for (int r = 0; r < 4; ++r) {
            const int k = r + 50 - s;
            if (0 <= k && k <= 50) macc[r] = fmaf(coeffs[k], xv, macc[r]);
        }
    }
    #pragma unroll
    for (int r = 0; r < 4; ++r)
        memout[(size_t)(b * TT + t0 + 4 * wv + r) * 64 + lane] = macc[r];

    // ---- t/u/x for (row=tid>>4, feats fq*4..fq*4+3) into regs ----
    const int row = tid >> 4, fq = tid & 15;
    const f32x4 xv4 = *(const f32x4*)(&xs[(50 + row) * 64 + fq * 4]);
    float tq[4], uq[4];
    #pragma unroll
    for (int q = 0; q < 4; ++q) {
        const float xi = xv4[q];
        tq[q] = fmaf(-2.f, rcpf(__expf(2.f * xi) + 1.f), 1.f);  // tanh
        uq[q] = __expf(-fabsf(xi));                             // e^-|x|
    }
    __syncthreads();                                    // bar2 (xs reads done)
    #pragma unroll
    for (int q = 0; q < 4; ++q) {
        const int f = fq * 4 + q;
        tS[f * 65 + row] = tq[q];
        uh[f * 66 + row] = __float2half(uq[q]);
        xh[f * 66 + row] = __float2half(xv4[q]);
    }
    __syncthreads();                                    // bar3

    // ---- coupling + proj: lane=row, 8 feats/wave, half j-range/group ----
    const int i0 = (wv & 7) * 8;
    const int jg = wv >> 3;
    float ti[8], ui[8];
    #pragma unroll
    for (int i = 0; i < 8; ++i) {
        ti[i] = tS[(i0 + i) * 65 + lane];
        ui[i] = __half2float(uh[(i0 + i) * 66 + lane]);
    }

    float cacc[8] = {0,0,0,0,0,0,0,0};
    float pacc[8] = {0,0,0,0,0,0,0,0};
    #pragma unroll 8
    for (int jj = 0; jj < 32; ++jj) {
        const int j = jg * 32 + jj;
        const float tj  = tS[j * 65 + lane];
        const float ujf = __half2float(uh[j * 66 + lane]);
        const float xjf = __half2float(xh[j * 66 + lane]);
        __half2 wpA[4], wpB[4];
        *(f32x4*)wpA = ((const f32x4*)(wpS + j * 64 + i0))[0];  // uniform b128
        *(f32x4*)wpB = ((const f32x4*)(wpS + j * 64 + i0))[1];
        #pragma unroll
        for (int i = 0; i < 8; ++i) {
            const __half2 wp2 = (i < 4) ? wpA[i] : wpB[i - 4];
            const float d1 = fmaf(-ti[i], tj, 1.f);     // 1 - ti*tj
            const float d2 = fmaf(ui[i], ujf, 1.f);     // 1 + ui*uj
            const float rr = rcpf(d1 * d2);
            cacc[i] = fmaf((ti[i] - tj) * __low2float(wp2), rr, cacc[i]);
            pacc[i] = fmaf(xjf, __high2float(wp2), pacc[i]);
        }
    }

    const float kappa = kap[0];
    const float ksum  = (1.f - __expf(-kappa * (float)(t0 + lane + 1))) *
                        rcpf(1.f - __expf(-kappa));
    __syncthreads();                                    // bar4 (plane reads done)
    if (jg == 1) {
        #pragma unroll
        for (int i = 0; i < 8; ++i)
            tS[(i0 + i) * 65 + lane] = fmaf(0.4f, cacc[i], 0.3f * pacc[i] * ksum);
    }
    __syncthreads();                                    // bar5
    if (jg == 0) {
        #pragma unroll
        for (int i = 0; i < 8; ++i) {
            const float v = fmaf(0.4f, cacc[i], 0.3f * (pacc[i] + pb[i0 + i]) * ksum)
                          + tS[(i0 + i) * 65 + lane];
            P2[(i0 + i) * 65 + lane] = v;
        }
    }
    __syncthreads();                                    // bar6

    // ---- final store: rows 4wv..4wv+3, transposed P2 read (pad-65 -> 2-way) ----
    #pragma unroll
    for (int r = 0; r < 4; ++r) {
        const int trw = 4 * wv + r;
        out[(size_t)(b * TT + t0 + trw) * 64 + lane] =
            fmaf(0.3f, macc[r], P2[lane * 65 + trw]);
    }
}

extern "C" void kernel_launch(void* const* d_in, const int* in_sizes, int n_in,
                              void* d_out, int out_size, void* d_ws, size_t ws_size,
                              hipStream_t stream) {
    const float* x   = (const float*)d_in[0];
    const float* W   = (const float*)d_in[1];
    const float* PW  = (const float*)d_in[2];
    const float* pb  = (const float*)d_in[3];
    const float* kap = (const float*)d_in[4];
    const float* cf  = (const float*)d_in[5];

    float* out    = (float*)d_out;
    float* memout = out + (size_t)4 * TT * FF;

    __half2* wp = (__half2*)d_ws;   // 16 KB

    hipLaunchKernelGGL(prep_kernel, dim3(1), dim3(64, 4), 0, stream, W, PW, wp);
    hipLaunchKernelGGL(mcao_main, dim3(4 * (TT / 64)), dim3(1024), 0, stream,
                       x, wp, pb, kap, cf, out, memout);
}

// Round 9
// 50.586 us; speedup vs baseline: 1.5523x; 1.5523x over previous
//
#include <hip/hip_runtime.h>
#include <hip/hip_fp16.h>
#include <math.h>

#define TT 8192
#define FF 64

typedef float f32x4 __attribute__((ext_vector_type(4)));

__device__ __forceinline__ float rcpf(float x) { return __builtin_amdgcn_rcpf(x); }

// ---- prep: wsmT[j*64+i] = softmax(W)[i][j]; pwT[j*64+i] = PW[i*64+j] ----
__global__ void prep_kernel(const float* __restrict__ W, const float* __restrict__ PW,
                            float* __restrict__ wsmT, float* __restrict__ pwT) {
    const int lane = threadIdx.x;   // j
    const int wv   = threadIdx.y;   // 0..3
    for (int it = 0; it < 16; ++it) {
        const int r = wv * 16 + it; // i
        float v = W[r * 64 + lane];
        float m = v;
        #pragma unroll
        for (int off = 32; off >= 1; off >>= 1)
            m = fmaxf(m, __shfl_xor(m, off, 64));
        float e = __expf(v - m);
        float s = e;
        #pragma unroll
        for (int off = 32; off >= 1; off >>= 1)
            s += __shfl_xor(s, off, 64);
        wsmT[lane * 64 + r] = e * rcpf(s);
        pwT[lane * 64 + r]  = PW[r * 64 + lane];
    }
}

// ---- fused main: 256 thr / 4 waves, 64-row tile, 16 feats/wave, full j ----
__global__ __launch_bounds__(256, 2)
void mcao_main(const float* __restrict__ x,
               const float* __restrict__ wsmT,
               const float* __restrict__ pwT,
               const float* __restrict__ pb,
               const float* __restrict__ kap,
               const float* __restrict__ coeffs,
               float* __restrict__ out,
               float* __restrict__ memout) {
    // LDS union:
    //   phase A: xs 114x64 f32            [0, 29184)
    //   phase B: tS 64x65 f32             [0, 16640)
    //            ux 64x66 half2 {u,x}     [16640, 33536)
    //   phase C: P2 64x65 f32             [16640, 33280)
    //   always:  wS 64x64 f32             [33536, 49920)
    //            pwS 64x64 f32            [49920, 66304)
    __shared__ __align__(16) char smem[66304];
    float*   xs  = (float*)smem;
    float*   tS  = (float*)smem;
    __half2* ux  = (__half2*)(smem + 16640);
    float*   P2  = (float*)(smem + 16640);
    float*   wS  = (float*)(smem + 33536);
    float*   pwS = (float*)(smem + 49920);

    const int tid  = threadIdx.x;
    const int lane = tid & 63;
    const int wv   = tid >> 6;              // 0..3

    // XCD-aware bijective swizzle (512 blocks -> 64 consecutive tiles/XCD)
    const int sw = ((int)blockIdx.x & 7) * 64 + ((int)blockIdx.x >> 3);
    const int b  = sw >> 7;
    const int t0 = (sw & 127) * 64;
    const float* xb = x + (size_t)b * TT * FF;

    // ---- stage xs rows [t0-50, t0+64), wS, pwS ----
    for (int i4 = tid; i4 < 114 * 16; i4 += 256) {
        const int s = i4 >> 4, f4 = i4 & 15, t = t0 - 50 + s;
        f32x4 v = {0.f, 0.f, 0.f, 0.f};
        if (t >= 0) v = *(const f32x4*)(xb + (size_t)t * 64 + f4 * 4);
        *(f32x4*)(&xs[i4 * 4]) = v;
    }
    #pragma unroll
    for (int k = 0; k < 4; ++k) {
        ((f32x4*)wS)[tid + 256 * k]  = ((const f32x4*)wsmT)[tid + 256 * k];
        ((f32x4*)pwS)[tid + 256 * k] = ((const f32x4*)pwT)[tid + 256 * k];
    }
    __syncthreads();                                    // bar1

    // ---- FIR: wave owns rows 16wv..16wv+15 ----
    float macc[16];
    #pragma unroll
    for (int r = 0; r < 16; ++r) macc[r] = 0.f;
    #pragma unroll
    for (int s = 0; s < 66; ++s) {
        const float xv = xs[(16 * wv + s) * 64 + lane];
        #pragma unroll
        for (int r = 0; r < 16; ++r) {
            const int k = r + 50 - s;
            if (0 <= k && k <= 50) macc[r] = fmaf(coeffs[k], xv, macc[r]);
        }
    }
    #pragma unroll
    for (int r = 0; r < 16; ++r)
        memout[(size_t)(b * TT + t0 + 16 * wv + r) * 64 + lane] = macc[r];

    // ---- t/u/x regs for planes: thread -> (row=tid>>2, feats (tid&3)*16..+15) ----
    const int prow = tid >> 2, pfq = tid & 3;
    float tq[16], uq[16], xq[16];
    #pragma unroll
    for (int c4 = 0; c4 < 4; ++c4) {
        const f32x4 xv4 = *(const f32x4*)(&xs[(50 + prow) * 64 + pfq * 16 + c4 * 4]);
        #pragma unroll
        for (int q = 0; q < 4; ++q) {
            const float xi = xv4[q];
            tq[c4 * 4 + q] = fmaf(-2.f, rcpf(__expf(2.f * xi) + 1.f), 1.f);  // tanh
            uq[c4 * 4 + q] = __expf(-fabsf(xi));                             // e^-|x|
            xq[c4 * 4 + q] = xi;
        }
    }
    __syncthreads();                                    // bar2 (xs reads done)
    #pragma unroll
    for (int c = 0; c < 16; ++c) {
        const int f = pfq * 16 + c;
        tS[f * 65 + prow] = tq[c];
        ux[f * 66 + prow] = __floats2half2_rn(uq[c], xq[c]);
    }
    __syncthreads();                                    // bar3

    // ---- coupling + proj: lane = row, 16 feats/wave, full j ----
    const int i0 = wv * 16;
    float ti[16], ui[16];
    #pragma unroll
    for (int i = 0; i < 16; ++i) {
        ti[i] = tS[(i0 + i) * 65 + lane];
        ui[i] = __low2float(ux[(i0 + i) * 66 + lane]);
    }

    float cacc[16], pacc[16];
    #pragma unroll
    for (int i = 0; i < 16; ++i) { cacc[i] = 0.f; pacc[i] = 0.f; }

    #pragma unroll 4
    for (int j = 0; j < 64; ++j) {
        const float  tj  = tS[j * 65 + lane];            // 2-way free
        const __half2 uxj = ux[j * 66 + lane];           // 2-way free
        const float  ujf = __low2float(uxj);
        const float  xjf = __high2float(uxj);
        f32x4 w4[4], p4[4];
        #pragma unroll
        for (int q = 0; q < 4; ++q) {                    // uniform b128 broadcasts
            w4[q] = *(const f32x4*)(&wS[j * 64 + i0 + 4 * q]);
            p4[q] = *(const f32x4*)(&pwS[j * 64 + i0 + 4 * q]);
        }
        #pragma unroll
        for (int i = 0; i < 16; ++i) {
            const float wij = w4[i >> 2][i & 3];
            const float pij = p4[i >> 2][i & 3];
            const float d1 = fmaf(-ti[i], tj, 1.f);      // 1 - ti*tj
            const float d2 = fmaf( ui[i], ujf, 1.f);     // 1 + ui*uj
            const float rr = rcpf(d1 * d2);
            cacc[i] = fmaf((ti[i] - tj) * wij, rr, cacc[i]);
            pacc[i] = fmaf(xjf, pij, pacc[i]);
        }
    }

    const float kappa = kap[0];
    const float ksum  = (1.f - __expf(-kappa * (float)(t0 + lane + 1))) *
                        rcpf(1.f - __expf(-kappa));      // lane = row
    __syncthreads();                                    // bar4 (plane reads done)
    #pragma unroll
    for (int i = 0; i < 16; ++i)
        P2[(i0 + i) * 65 + lane] =
            fmaf(0.4f, cacc[i], 0.3f * (pacc[i] + pb[i0 + i]) * ksum);
    __syncthreads();                                    // bar5

    // ---- final store: wave rows 16wv..16wv+15, lane = feature ----
    #pragma unroll
    for (int r = 0; r < 16; ++r) {
        const int row = 16 * wv + r;
        out[(size_t)(b * TT + t0 + row) * 64 + lane] =
            fmaf(0.3f, macc[r], P2[lane * 65 + row]);    // (lane+row)%32: conflict-free
    }
}

extern "C" void kernel_launch(void* const* d_in, const int* in_sizes, int n_in,
                              void* d_out, int out_size, void* d_ws, size_t ws_size,
                              hipStream_t stream) {
    const float* x   = (const float*)d_in[0];
    const float* W   = (const float*)d_in[1];
    const float* PW  = (const float*)d_in[2];
    const float* pb  = (const float*)d_in[3];
    const float* kap = (const float*)d_in[4];
    const float* cf  = (const float*)d_in[5];

    float* out    = (float*)d_out;
    float* memout = out + (size_t)4 * TT * FF;

    float* wsmT = (float*)d_ws;          // 16 KB
    float* pwT  = wsmT + 64 * 64;        // 16 KB

    hipLaunchKernelGGL(prep_kernel, dim3(1), dim3(64, 4), 0, stream, W, PW, wsmT, pwT);
    hipLaunchKernelGGL(mcao_main, dim3(4 * (TT / 64)), dim3(256), 0, stream,
                       x, wsmT, pwT, pb, kap, cf, out, memout);
}